// Round 3
// 602.894 us; speedup vs baseline: 1.0186x; 1.0186x over previous
//
#include <hip/hip_runtime.h>

// Cost volume: left,right [B=2, C=32, H=128, W=256] fp32, max_disp D=32.
// out [B, 2C, D, H, W]:
//   c2 <  C: out = (w+d < W)  ? left [b,c2,  h, w+d] : 0
//   c2 >= C: out = (w-d >= 0) ? right[b,c2-C,h, w-d] : 0
//
// Store-BW-bound: 512 MiB out, 16 MiB in (cached, 32x reuse).
// Structure: grid-stride with stride = 2048*256 float4 = 2^21 floats.
// Adding the stride to the flat index leaves (w,h,d) unchanged and
// advances c2 by +2 (wrapping into b). Each thread decodes ONCE,
// precomputes 4 clamped indices + 4 boundary masks ONCE, then runs
// 64 sweeps of {4 cached loads, 1 NT float4 store}. Sweeps 0-15
// left/b=0, 16-31 right/b=0, 32-47 left/b=1, 48-63 right/b=1.
// All control flow wave-uniform. 2048 blocks = 8 wg/CU.
// NT store uses a native clang ext_vector (HIP float4 is a class and
// is rejected by __builtin_nontemporal_store).

typedef float vfloat4 __attribute__((ext_vector_type(4)));

__global__ __launch_bounds__(256) void costvol_kernel(
        const float* __restrict__ left,
        const float* __restrict__ right,
        float* __restrict__ out) {
    constexpr int W = 256, H = 128, C = 32;
    constexpr unsigned NBLK    = 2048u;
    constexpr unsigned STRIDE4 = NBLK * 256u;        // 2^19 float4 per sweep

    unsigned n0 = blockIdx.x * 256u + threadIdx.x;   // [0, 2^19)
    // flat float index = n*4 = w + W*(h + H*(d + D*(c2 + 2C*b)))
    unsigned w  = (n0 & 63u) << 2;      // 64 float4 per row
    unsigned r  = n0 >> 6;
    unsigned h  = r & 127u; r >>= 7;    // H = 128
    unsigned d  = r & 31u;  r >>= 5;    // D = 32
    unsigned c0 = r;                    // {0,1}: low bits of c2; +2 per sweep

    int bl = (int)(w + d);              // left  gather base: w+d
    int br = (int)w - (int)d;           // right gather base: w-d

    // Loop-invariant clamped indices + validity masks (per component).
    int  il[4], ir[4];
    bool ml[4], mr[4];
#pragma unroll
    for (int j = 0; j < 4; ++j) {
        ml[j] = (bl + j) < W;   il[j] = ml[j] ? (bl + j) : 0;
        mr[j] = (br + j) >= 0;  ir[j] = mr[j] ? (br + j) : 0;
    }

    const size_t chstep = (size_t)H * W;   // floats per (b,c) channel plane
    const size_t rowoff = (size_t)h * W;

    vfloat4* out4 = reinterpret_cast<vfloat4*>(out) + n0;

#pragma unroll
    for (int b = 0; b < 2; ++b) {
        // ---- left phase: sweeps cover c2 = c0, c0+2, ..., c0+30 ----
        const float* rowL = left + ((size_t)(b * C) + c0) * chstep + rowoff;
#pragma unroll
        for (int it = 0; it < 16; ++it) {
            vfloat4 v;
            v.x = ml[0] ? rowL[il[0]] : 0.f;
            v.y = ml[1] ? rowL[il[1]] : 0.f;
            v.z = ml[2] ? rowL[il[2]] : 0.f;
            v.w = ml[3] ? rowL[il[3]] : 0.f;
            __builtin_nontemporal_store(v, out4);
            out4 += STRIDE4;
            rowL += 2 * chstep;
        }
        // ---- right phase: c2 = 32+c0, 34+c0, ..., 62+c0 ----
        const float* rowR = right + ((size_t)(b * C) + c0) * chstep + rowoff;
#pragma unroll
        for (int it = 0; it < 16; ++it) {
            vfloat4 v;
            v.x = mr[0] ? rowR[ir[0]] : 0.f;
            v.y = mr[1] ? rowR[ir[1]] : 0.f;
            v.z = mr[2] ? rowR[ir[2]] : 0.f;
            v.w = mr[3] ? rowR[ir[3]] : 0.f;
            __builtin_nontemporal_store(v, out4);
            out4 += STRIDE4;
            rowR += 2 * chstep;
        }
    }
}

extern "C" void kernel_launch(void* const* d_in, const int* in_sizes, int n_in,
                              void* d_out, int out_size, void* d_ws, size_t ws_size,
                              hipStream_t stream) {
    const float* left  = (const float*)d_in[0];
    const float* right = (const float*)d_in[1];
    float* out = (float*)d_out;

    // out_size = 134,217,728 floats = 2^25 float4 = 64 sweeps of 2048*256.
    costvol_kernel<<<2048, 256, 0, stream>>>(left, right, out);
}

// Round 4
// 540.401 us; speedup vs baseline: 1.1364x; 1.1156x over previous
//
#include <hip/hip_runtime.h>

// Cost volume: left,right [B=2, C=32, H=128, W=256] fp32, max_disp D=32.
// out [B, 2C, D, H, W]:
//   c2 <  C: out = (w+d < W)  ? left [b,c2,  h, w+d] : 0
//   c2 >= C: out = (w-d >= 0) ? right[b,c2-C,h, w-d] : 0
//
// Fill-shaped structure: thread owns (b, c, h, w4). It loads its 36-float
// halo of the left row and the 36-float halo of the right row ONCE
// (9 + 9 float4 loads, OOB zeroed at float4 granularity), then issues
// 64 register-sourced float4 stores (32 left disparities + 32 right).
// No load feeds any store directly -> the store stream runs at fill
// speed instead of stalling on per-store gather round trips (the ~2 TB/s
// ceiling both previous variants hit).
//   left  store d: elements left[4*w4 + d + j] = l[d + j]      (j=0..3)
//   right store d: elements right[4*w4 + j - d] = r[32 - d + j]
// All array indices static after unroll (no scratch). Lanes = consecutive
// w4 -> every wave store is 1 KiB contiguous. Grid 2048x256 = 8 wg/CU.

typedef float vfloat4 __attribute__((ext_vector_type(4)));

__global__ __launch_bounds__(256) void costvol_kernel(
        const float* __restrict__ left,
        const float* __restrict__ right,
        float* __restrict__ out) {
    constexpr int W4 = 64, H = 128, D = 32, C = 32;

    const unsigned tid = threadIdx.x;
    const unsigned w4  = tid & 63u;          // float4 position in row
    const unsigned hlo = tid >> 6;           // 0..3
    const unsigned bid = blockIdx.x;         // 0..2047 = 32(h_hi)*32(c)*2(b)
    const unsigned h   = (bid & 31u) * 4u + hlo;
    const unsigned c   = (bid >> 5) & 31u;
    const unsigned b   = bid >> 10;

    const size_t inoff = ((size_t)(b * C + c) * H + h) * 256;   // floats
    const vfloat4* lrow = reinterpret_cast<const vfloat4*>(left  + inoff);
    const vfloat4* rrow = reinterpret_cast<const vfloat4*>(right + inoff);

    // out float4 index: w4 + 64*(h + 128*(d + 32*(c2 + 64*b)))
    const size_t dstride = (size_t)W4 * H;                       // 8192
    vfloat4* outL = reinterpret_cast<vfloat4*>(out)
                  + (size_t)w4
                  + (size_t)W4 * ((size_t)h + (size_t)H * D * ((size_t)c + 2u * C * (size_t)b));
    vfloat4* outR = outL + (size_t)C * D * dstride;              // c2 += C

    const vfloat4 zero4 = {0.f, 0.f, 0.f, 0.f};

    // ---- left phase: l[t] = (4*w4 + t < 256) ? left[row, 4*w4+t] : 0 ----
    float l[36];
#pragma unroll
    for (int k = 0; k < 9; ++k) {
        vfloat4 v = (w4 + (unsigned)k < (unsigned)W4) ? lrow[w4 + k] : zero4;
        l[4*k+0] = v.x; l[4*k+1] = v.y; l[4*k+2] = v.z; l[4*k+3] = v.w;
    }
#pragma unroll
    for (int d = 0; d < D; ++d) {
        vfloat4 q = { l[d], l[d+1], l[d+2], l[d+3] };
        outL[(size_t)d * dstride] = q;
    }

    // ---- right phase: r[t] = (4*w4 - 32 + t >= 0) ? right[row, 4*w4-32+t] : 0
    float r[36];
#pragma unroll
    for (int m = 0; m < 9; ++m) {
        vfloat4 v = (w4 + (unsigned)m >= 8u) ? rrow[(int)(w4 + m) - 8] : zero4;
        r[4*m+0] = v.x; r[4*m+1] = v.y; r[4*m+2] = v.z; r[4*m+3] = v.w;
    }
#pragma unroll
    for (int d = 0; d < D; ++d) {
        vfloat4 q = { r[32-d], r[33-d], r[34-d], r[35-d] };
        outR[(size_t)d * dstride] = q;
    }
}

extern "C" void kernel_launch(void* const* d_in, const int* in_sizes, int n_in,
                              void* d_out, int out_size, void* d_ws, size_t ws_size,
                              hipStream_t stream) {
    const float* left  = (const float*)d_in[0];
    const float* right = (const float*)d_in[1];
    float* out = (float*)d_out;

    // 2048 blocks x 256 threads x 64 float4 stores = 2^25 float4 = out_size/4.
    costvol_kernel<<<2048, 256, 0, stream>>>(left, right, out);
}